// Round 3
// baseline (2770.225 us; speedup 1.0000x reference)
//
#include <hip/hip_runtime.h>

#define HID   128
#define GATES 512
#define BATCH 256
#define SEQ   512
#define INSZ  10
#define MB    16                 // batch rows per block (MFMA M)
#define NBLK  (BATCH / MB)       // 16 blocks
#define NTHR  512                // 8 waves
#define HSTR  136                // fp16 row stride (272 B: uniform 8-lane/bank-group b128 reads)

typedef _Float16 half8  __attribute__((ext_vector_type(8)));
typedef _Float16 half4  __attribute__((ext_vector_type(4)));
typedef float    floatx4 __attribute__((ext_vector_type(4)));

#define MFMA16(A, B, C) __builtin_amdgcn_mfma_f32_16x16x32_f16(A, B, C, 0, 0, 0)

// xg0 element count: [blk][t][gg 0..3][col 0..127][row 0..15] fp16
#define XG_HALF_PER_T  8192            // 4*128*16
#define XG_BYTES ((size_t)NBLK * SEQ * XG_HALF_PER_T * 2)   // 134217728

__device__ __forceinline__ float sigmf(float x)    { return 1.0f / (1.0f + __expf(-x)); }
__device__ __forceinline__ float tanhfast(float x) { return 2.0f / (1.0f + __expf(-2.0f * x)) - 1.0f; }

__device__ __forceinline__ half8 load_wfrag(const float* rowbase, int k0)
{
    const float4* p = (const float4*)(rowbase + k0);
    float4 a = p[0], b = p[1];
    half8 r;
    r[0] = (_Float16)a.x; r[1] = (_Float16)a.y; r[2] = (_Float16)a.z; r[3] = (_Float16)a.w;
    r[4] = (_Float16)b.x; r[5] = (_Float16)b.y; r[6] = (_Float16)b.z; r[7] = (_Float16)b.w;
    return r;
}

// =================== Kernel 1: xg0 = x @ W_ih0^T + b_ih0 + b_hh0 ===================
// grid (NBLK, 32), 512 thr; each block: 16 t's, thread = one gate row.
__global__ __launch_bounds__(512, 2)
void xg0_precompute(const float* __restrict__ x,
                    const float* __restrict__ w_ih0,
                    const float* __restrict__ b_ih0, const float* __restrict__ b_hh0,
                    _Float16* __restrict__ xg0)
{
    const int blk = blockIdx.x;
    const int tq  = blockIdx.y;
    const int g   = threadIdx.x;          // gate row 0..511
    const int b0  = blk * MB;
    const int col = g & 127, gg = g >> 7;

    __shared__ float xsh[MB][12];

    float wrow[INSZ];
#pragma unroll
    for (int d = 0; d < INSZ; ++d) wrow[d] = w_ih0[g * INSZ + d];
    const float bias = b_ih0[g] + b_hh0[g];

    for (int tt = 0; tt < 16; ++tt) {
        const int t = tq * 16 + tt;
        __syncthreads();
        if (g < MB * INSZ) {
            int r = g / INSZ, d = g - r * INSZ;
            xsh[r][d] = x[((size_t)(b0 + r) * SEQ + t) * INSZ + d];
        }
        __syncthreads();
        half8 o0, o1;
#pragma unroll
        for (int r = 0; r < MB; ++r) {
            float a = bias;
#pragma unroll
            for (int d = 0; d < INSZ; ++d) a += xsh[r][d] * wrow[d];
            if (r < 8) o0[r] = (_Float16)a; else o1[r - 8] = (_Float16)a;
        }
        _Float16* dst = xg0 + (((size_t)blk * SEQ + t) * 4 + gg) * 2048 + (size_t)col * MB;
        *(half8*)(dst)     = o0;
        *(half8*)(dst + 8) = o1;
    }
}

// =================== Kernel 2: fused 2-layer recurrence, 513 pipelined steps ===================
__global__ __launch_bounds__(NTHR, 2)
void lstm_fused2(const float* __restrict__ w_hh0,
                 const float* __restrict__ w_ih1, const float* __restrict__ w_hh1,
                 const float* __restrict__ b_ih1, const float* __restrict__ b_hh1,
                 const float* __restrict__ fc_w,  const float* __restrict__ fc_b,
                 const _Float16* __restrict__ xg0,
                 float* __restrict__ out)
{
    const int tid  = threadIdx.x;
    const int lane = tid & 63;
    const int wv   = tid >> 6;
    const int m16  = lane & 15;
    const int quad = lane >> 4;
    const int col  = (wv << 4) + m16;
    const int b0   = blockIdx.x * MB;

    __shared__ __align__(16) _Float16 hA[2][MB * HSTR];   // layer-0 h ping-pong (shared as L1 input)
    __shared__ __align__(16) _Float16 hB[2][MB * HSTR];   // layer-1 h ping-pong

    // ---- weight fragments ----
    half8 Whh0f[4][4], Wih1f[4][4], Whh1f[4][4];
    float bias1[4];
#pragma unroll
    for (int g = 0; g < 4; ++g) {
        const int gr = g * HID + col;
        bias1[g] = b_ih1[gr] + b_hh1[gr];
#pragma unroll
        for (int ks = 0; ks < 4; ++ks) {
            Whh0f[g][ks] = load_wfrag(w_hh0 + (size_t)gr * HID, ks * 32 + quad * 8);
            Wih1f[g][ks] = load_wfrag(w_ih1 + (size_t)gr * HID, ks * 32 + quad * 8);
            Whh1f[g][ks] = load_wfrag(w_hh1 + (size_t)gr * HID, ks * 32 + quad * 8);
        }
    }

    // xg0 prefetch (time 0)
    const _Float16* xgB = xg0 + (size_t)blockIdx.x * SEQ * XG_HALF_PER_T
                        + (size_t)col * MB + quad * 4;
    uint2 xgb[4];
#pragma unroll
    for (int g = 0; g < 4; ++g)
        xgb[g] = *(const uint2*)(const void*)(xgB + (size_t)g * 2048);

    // zero both ping-pong sets
    {
        int* z = (int*)&hA[0][0];
        for (int i = tid; i < 2 * 2 * MB * HSTR / 2; i += NTHR) z[i] = 0;
    }
    __syncthreads();

    const int laneRd = m16 * HSTR + quad * 8;
    const int wrBase = (quad * 4) * HSTR + col;

    float c0[4] = {0.f, 0.f, 0.f, 0.f};
    float c1[4] = {0.f, 0.f, 0.f, 0.f};

    for (int t = 0; t <= SEQ; ++t) {
        const int p = t & 1;

        // ---- L0 acc init from prefetched xg, then issue next prefetch ----
        floatx4 A0, A1, A2, A3;
        if (t < SEQ) {
            half4 g0 = __builtin_bit_cast(half4, xgb[0]);
            half4 g1 = __builtin_bit_cast(half4, xgb[1]);
            half4 g2 = __builtin_bit_cast(half4, xgb[2]);
            half4 g3 = __builtin_bit_cast(half4, xgb[3]);
#pragma unroll
            for (int e = 0; e < 4; ++e) {
                A0[e] = (float)g0[e]; A1[e] = (float)g1[e];
                A2[e] = (float)g2[e]; A3[e] = (float)g3[e];
            }
        }
        if (t + 1 < SEQ) {
            const _Float16* src = xgB + (size_t)(t + 1) * XG_HALF_PER_T;
#pragma unroll
            for (int g = 0; g < 4; ++g)
                xgb[g] = *(const uint2*)(const void*)(src + (size_t)g * 2048);
        }

        // ---- shared A-fragments: h_L0[t-1] (used by L0 recurrence AND L1 input) ----
        const _Float16* haB = &hA[p ^ 1][0] + laneRd;
        half8 ha0 = *(const half8*)(haB);
        half8 ha1 = *(const half8*)(haB + 32);
        half8 ha2 = *(const half8*)(haB + 64);
        half8 ha3 = *(const half8*)(haB + 96);

        // ---- layer 0: time t ----
        if (t < SEQ) {
            A0 = MFMA16(ha0, Whh0f[0][0], A0); A1 = MFMA16(ha0, Whh0f[1][0], A1);
            A2 = MFMA16(ha0, Whh0f[2][0], A2); A3 = MFMA16(ha0, Whh0f[3][0], A3);
            A0 = MFMA16(ha1, Whh0f[0][1], A0); A1 = MFMA16(ha1, Whh0f[1][1], A1);
            A2 = MFMA16(ha1, Whh0f[2][1], A2); A3 = MFMA16(ha1, Whh0f[3][1], A3);
            A0 = MFMA16(ha2, Whh0f[0][2], A0); A1 = MFMA16(ha2, Whh0f[1][2], A1);
            A2 = MFMA16(ha2, Whh0f[2][2], A2); A3 = MFMA16(ha2, Whh0f[3][2], A3);
            A0 = MFMA16(ha3, Whh0f[0][3], A0); A1 = MFMA16(ha3, Whh0f[1][3], A1);
            A2 = MFMA16(ha3, Whh0f[2][3], A2); A3 = MFMA16(ha3, Whh0f[3][3], A3);

            _Float16* hw = &hA[p][0] + wrBase;
#pragma unroll
            for (int e = 0; e < 4; ++e) {
                float iv = sigmf(A0[e]);
                float fv = sigmf(A1[e]);
                float gv = tanhfast(A2[e]);
                float ov = sigmf(A3[e]);
                c0[e] = fv * c0[e] + iv * gv;
                hw[e * HSTR] = (_Float16)(ov * tanhfast(c0[e]));
            }
        }

        // ---- layer 1: time t-1 ----
        if (t > 0) {
            floatx4 B0 = {bias1[0], bias1[0], bias1[0], bias1[0]};
            floatx4 B1 = {bias1[1], bias1[1], bias1[1], bias1[1]};
            floatx4 B2 = {bias1[2], bias1[2], bias1[2], bias1[2]};
            floatx4 B3 = {bias1[3], bias1[3], bias1[3], bias1[3]};
            // input projection: h1[t-1] (= ha frags) @ W_ih1^T
            B0 = MFMA16(ha0, Wih1f[0][0], B0); B1 = MFMA16(ha0, Wih1f[1][0], B1);
            B2 = MFMA16(ha0, Wih1f[2][0], B2); B3 = MFMA16(ha0, Wih1f[3][0], B3);
            B0 = MFMA16(ha1, Wih1f[0][1], B0); B1 = MFMA16(ha1, Wih1f[1][1], B1);
            B2 = MFMA16(ha1, Wih1f[2][1], B2); B3 = MFMA16(ha1, Wih1f[3][1], B3);
            B0 = MFMA16(ha2, Wih1f[0][2], B0); B1 = MFMA16(ha2, Wih1f[1][2], B1);
            B2 = MFMA16(ha2, Wih1f[2][2], B2); B3 = MFMA16(ha2, Wih1f[3][2], B3);
            B0 = MFMA16(ha3, Wih1f[0][3], B0); B1 = MFMA16(ha3, Wih1f[1][3], B1);
            B2 = MFMA16(ha3, Wih1f[2][3], B2); B3 = MFMA16(ha3, Wih1f[3][3], B3);
            // recurrent: h2[t-2] @ W_hh1^T
            const _Float16* hbB = &hB[p][0] + laneRd;
            half8 hb0 = *(const half8*)(hbB);
            half8 hb1 = *(const half8*)(hbB + 32);
            half8 hb2 = *(const half8*)(hbB + 64);
            half8 hb3 = *(const half8*)(hbB + 96);
            B0 = MFMA16(hb0, Whh1f[0][0], B0); B1 = MFMA16(hb0, Whh1f[1][0], B1);
            B2 = MFMA16(hb0, Whh1f[2][0], B2); B3 = MFMA16(hb0, Whh1f[3][0], B3);
            B0 = MFMA16(hb1, Whh1f[0][1], B0); B1 = MFMA16(hb1, Whh1f[1][1], B1);
            B2 = MFMA16(hb1, Whh1f[2][1], B2); B3 = MFMA16(hb1, Whh1f[3][1], B3);
            B0 = MFMA16(hb2, Whh1f[0][2], B0); B1 = MFMA16(hb2, Whh1f[1][2], B1);
            B2 = MFMA16(hb2, Whh1f[2][2], B2); B3 = MFMA16(hb2, Whh1f[3][2], B3);
            B0 = MFMA16(hb3, Whh1f[0][3], B0); B1 = MFMA16(hb3, Whh1f[1][3], B1);
            B2 = MFMA16(hb3, Whh1f[2][3], B2); B3 = MFMA16(hb3, Whh1f[3][3], B3);

            _Float16* hw2 = &hB[p ^ 1][0] + wrBase;
#pragma unroll
            for (int e = 0; e < 4; ++e) {
                float iv = sigmf(B0[e]);
                float fv = sigmf(B1[e]);
                float gv = tanhfast(B2[e]);
                float ov = sigmf(B3[e]);
                c1[e] = fv * c1[e] + iv * gv;
                hw2[e * HSTR] = (_Float16)(ov * tanhfast(c1[e]));
            }
        }
        __syncthreads();
    }

    // ---- FC epilogue: final h2 is in hB[1] (t=512: p=0, wrote hB[p^1]) ----
    if (tid < 160) {
        const int cls = tid >> 4, b = tid & 15;
        float a = fc_b[cls];
        const float* wr = fc_w + cls * HID;
        const _Float16* hb1 = &hB[1][0] + b * HSTR;
#pragma unroll 8
        for (int k = 0; k < HID; ++k) a += wr[k] * (float)hb1[k];
        out[(size_t)(b0 + b) * 10 + cls] = a;
    }
}

// =================== Fallback path (proven R1 kernels, needs 64 MiB ws) ===================
__global__ __launch_bounds__(512, 2)
void fb_layer0(const float* __restrict__ x, const float* __restrict__ w_ih,
               const float* __restrict__ w_hh, const float* __restrict__ b_ih,
               const float* __restrict__ b_hh, float* __restrict__ h1out)
{
    const int b = blockIdx.x;
    const int g = threadIdx.x;
    __shared__ float h_sh[HID];
    __shared__ float c_sh[HID];
    __shared__ float gates_sh[GATES];
    __shared__ float x_sh[INSZ];
    float whh[HID];
    const float4* wrow = (const float4*)(w_hh + g * HID);
#pragma unroll
    for (int k4 = 0; k4 < HID / 4; ++k4) {
        float4 v = wrow[k4];
        whh[4*k4+0] = v.x; whh[4*k4+1] = v.y; whh[4*k4+2] = v.z; whh[4*k4+3] = v.w;
    }
    float wih[INSZ];
#pragma unroll
    for (int d = 0; d < INSZ; ++d) wih[d] = w_ih[g * INSZ + d];
    const float bias = b_ih[g] + b_hh[g];
    if (g < HID) { h_sh[g] = 0.0f; c_sh[g] = 0.0f; }
    const float* xb = x + (size_t)b * SEQ * INSZ;
    float*       hb = h1out + (size_t)b * SEQ * HID;
    for (int t = 0; t < SEQ; ++t) {
        if (g < INSZ) x_sh[g] = xb[t * INSZ + g];
        __syncthreads();
        float acc = bias;
#pragma unroll
        for (int d = 0; d < INSZ; ++d) acc += x_sh[d] * wih[d];
        const float4* h4p = (const float4*)h_sh;
#pragma unroll
        for (int k4 = 0; k4 < HID / 4; ++k4) {
            float4 h4 = h4p[k4];
            acc += h4.x * whh[4*k4+0] + h4.y * whh[4*k4+1]
                 + h4.z * whh[4*k4+2] + h4.w * whh[4*k4+3];
        }
        gates_sh[g] = acc;
        __syncthreads();
        if (g < HID) {
            float iv = sigmf(gates_sh[g]);
            float fv = sigmf(gates_sh[g + HID]);
            float gv = tanhfast(gates_sh[g + 2 * HID]);
            float ov = sigmf(gates_sh[g + 3 * HID]);
            float c  = fv * c_sh[g] + iv * gv;
            float h  = ov * tanhfast(c);
            c_sh[g] = c; h_sh[g] = h;
            hb[t * HID + g] = h;
        }
    }
}

__global__ __launch_bounds__(512, 2)
void fb_layer1(const float* __restrict__ h1, const float* __restrict__ w_ih,
               const float* __restrict__ w_hh, const float* __restrict__ b_ih,
               const float* __restrict__ b_hh, const float* __restrict__ fc_w,
               const float* __restrict__ fc_b, float* __restrict__ out)
{
    const int b = blockIdx.x;
    const int g = threadIdx.x;
    __shared__ float xg_sh[32][GATES];
    __shared__ float h1_sh[32][HID];
    __shared__ float h_sh[HID];
    __shared__ float c_sh[HID];
    __shared__ float gates_sh[GATES];
    float whh[HID];
    const float4* wrow = (const float4*)(w_hh + g * HID);
#pragma unroll
    for (int k4 = 0; k4 < HID / 4; ++k4) {
        float4 v = wrow[k4];
        whh[4*k4+0] = v.x; whh[4*k4+1] = v.y; whh[4*k4+2] = v.z; whh[4*k4+3] = v.w;
    }
    const float bias = b_ih[g] + b_hh[g];
    if (g < HID) { h_sh[g] = 0.0f; c_sh[g] = 0.0f; }
    for (int chunk = 0; chunk < SEQ / 32; ++chunk) {
        const int t0 = chunk * 32;
        const float4* src = (const float4*)(h1 + ((size_t)b * SEQ + t0) * HID);
        float4*       dst = (float4*)&h1_sh[0][0];
#pragma unroll
        for (int i = 0; i < 2; ++i) dst[g + 512 * i] = src[g + 512 * i];
        __syncthreads();
        float acc[32];
#pragma unroll
        for (int tt = 0; tt < 32; ++tt) acc[tt] = bias;
        const float4* wi = (const float4*)(w_ih + g * HID);
        for (int k4 = 0; k4 < HID / 4; ++k4) {
            float4 wv = wi[k4];
#pragma unroll
            for (int tt = 0; tt < 32; ++tt) {
                float4 h4 = *(const float4*)&h1_sh[tt][4 * k4];
                acc[tt] += h4.x * wv.x + h4.y * wv.y + h4.z * wv.z + h4.w * wv.w;
            }
        }
#pragma unroll
        for (int tt = 0; tt < 32; ++tt) xg_sh[tt][g] = acc[tt];
        __syncthreads();
        for (int tt = 0; tt < 32; ++tt) {
            float a = xg_sh[tt][g];
            const float4* h4p = (const float4*)h_sh;
#pragma unroll
            for (int k4 = 0; k4 < HID / 4; ++k4) {
                float4 h4 = h4p[k4];
                a += h4.x * whh[4*k4+0] + h4.y * whh[4*k4+1]
                   + h4.z * whh[4*k4+2] + h4.w * whh[4*k4+3];
            }
            gates_sh[g] = a;
            __syncthreads();
            if (g < HID) {
                float iv = sigmf(gates_sh[g]);
                float fv = sigmf(gates_sh[g + HID]);
                float gv = tanhfast(gates_sh[g + 2 * HID]);
                float ov = sigmf(gates_sh[g + 3 * HID]);
                float c  = fv * c_sh[g] + iv * gv;
                float h  = ov * tanhfast(c);
                c_sh[g] = c; h_sh[g] = h;
            }
            __syncthreads();
        }
    }
    if (g < 10) {
        float a = fc_b[g];
        const float* wr = fc_w + g * HID;
#pragma unroll
        for (int k = 0; k < HID; ++k) a += wr[k] * h_sh[k];
        out[b * 10 + g] = a;
    }
}

extern "C" void kernel_launch(void* const* d_in, const int* in_sizes, int n_in,
                              void* d_out, int out_size, void* d_ws, size_t ws_size,
                              hipStream_t stream) {
    (void)in_sizes; (void)n_in; (void)out_size;
    const float* x     = (const float*)d_in[0];
    const float* w_ih0 = (const float*)d_in[1];
    const float* w_hh0 = (const float*)d_in[2];
    const float* b_ih0 = (const float*)d_in[3];
    const float* b_hh0 = (const float*)d_in[4];
    const float* w_ih1 = (const float*)d_in[5];
    const float* w_hh1 = (const float*)d_in[6];
    const float* b_ih1 = (const float*)d_in[7];
    const float* b_hh1 = (const float*)d_in[8];
    const float* fc_w  = (const float*)d_in[9];
    const float* fc_b  = (const float*)d_in[10];
    float* out = (float*)d_out;

    if (ws_size >= XG_BYTES) {
        _Float16* xg0 = (_Float16*)d_ws;
        xg0_precompute<<<dim3(NBLK, 32), 512, 0, stream>>>(x, w_ih0, b_ih0, b_hh0, xg0);
        lstm_fused2<<<NBLK, NTHR, 0, stream>>>(w_hh0, w_ih1, w_hh1, b_ih1, b_hh1,
                                               fc_w, fc_b, xg0, out);
    } else {
        float* h1 = (float*)d_ws;   // 64 MiB fallback path
        fb_layer0<<<BATCH, 512, 0, stream>>>(x, w_ih0, w_hh0, b_ih0, b_hh0, h1);
        fb_layer1<<<BATCH, 512, 0, stream>>>(h1, w_ih1, w_hh1, b_ih1, b_hh1,
                                             fc_w, fc_b, out);
    }
}

// Round 6
// 2231.248 us; speedup vs baseline: 1.2416x; 1.2416x over previous
//
#include <hip/hip_runtime.h>

#define HID   128
#define BATCH 256
#define SEQ   512
#define INSZ  10
#define MB    16                 // batch rows per block (MFMA M)
#define NBLK  (BATCH / MB)       // 16 blocks
#define NTHR  512                // 8 waves
#define HSTR  136                // fp16 row stride for h ping-pong (bank-conflict pad)
#define XSTR  24                 // fp16 row stride for x staging (K padded 10->16, +8 pad)
#define XCH   8                  // x chunk (timesteps per staged chunk)

typedef _Float16 half8  __attribute__((ext_vector_type(8)));
typedef _Float16 half4  __attribute__((ext_vector_type(4)));
typedef _Float16 half2v __attribute__((ext_vector_type(2)));
typedef float    floatx4 __attribute__((ext_vector_type(4)));

#define MFMA32(A, B, C) __builtin_amdgcn_mfma_f32_16x16x32_f16(A, B, C, 0, 0, 0)
// NOTE: legacy K=16 intrinsic has no underscore before f16 on gfx950
#define MFMA16(A, B, C) __builtin_amdgcn_mfma_f32_16x16x16f16(A, B, C, 0, 0, 0)

// v_rcp + one Newton iteration: ~0.5 ulp (vs ~1 ulp raw rcp which compounded to
// 3.9e-3 absmax through the 512-step forget-gate chain in R5), 3 ops vs ~11 for
// the IEEE divide sequence.
__device__ __forceinline__ float fastrcp(float d)
{
    float r = __builtin_amdgcn_rcpf(d);
    return r * (2.0f - d * r);
}
__device__ __forceinline__ float sigmf(float x)    { return fastrcp(1.0f + __expf(-x)); }
__device__ __forceinline__ float tanhfast(float x) { return 2.0f * fastrcp(1.0f + __expf(-2.0f * x)) - 1.0f; }

__device__ __forceinline__ half8 load_wfrag(const float* rowbase, int k0)
{
    const float4* p = (const float4*)(rowbase + k0);
    float4 a = p[0], b = p[1];
    half8 r;
    r[0] = (_Float16)a.x; r[1] = (_Float16)a.y; r[2] = (_Float16)a.z; r[3] = (_Float16)a.w;
    r[4] = (_Float16)b.x; r[5] = (_Float16)b.y; r[6] = (_Float16)b.z; r[7] = (_Float16)b.w;
    return r;
}

// ===== fused 2-layer LSTM: 513 pipelined steps, one barrier per step, no global ops
// ===== in the steady-state step except a coalesced x prefetch every 8 steps.
__global__ __launch_bounds__(NTHR, 2)
void lstm_fused3(const float* __restrict__ x,
                 const float* __restrict__ w_ih0, const float* __restrict__ w_hh0,
                 const float* __restrict__ b_ih0, const float* __restrict__ b_hh0,
                 const float* __restrict__ w_ih1, const float* __restrict__ w_hh1,
                 const float* __restrict__ b_ih1, const float* __restrict__ b_hh1,
                 const float* __restrict__ fc_w,  const float* __restrict__ fc_b,
                 float* __restrict__ out)
{
    const int tid  = threadIdx.x;
    const int lane = tid & 63;
    const int wv   = tid >> 6;        // wave -> hidden cols [16wv, 16wv+16)
    const int m16  = lane & 15;
    const int quad = lane >> 4;
    const int col  = (wv << 4) + m16;
    const int b0   = blockIdx.x * MB;

    __shared__ __align__(16) _Float16 xs[2][XCH * MB * XSTR];  // 12.0 KB
    __shared__ __align__(16) _Float16 hA[2][MB * HSTR];        // 8.5 KB (layer-0 h, shared as L1 input)
    __shared__ __align__(16) _Float16 hB[2][MB * HSTR];        // 8.5 KB (layer-1 h)

    // ---- weight fragments (resident in regs/AGPRs) ----
    half8 Whh0f[4][4], Wih1f[4][4], Whh1f[4][4];
    half4 Wih0f[4];                   // K=16 (padded from 10) -> 16x16x16 MFMA
    float bias0[4], bias1[4];
#pragma unroll
    for (int g = 0; g < 4; ++g) {
        const int gr = g * HID + col;
        bias0[g] = b_ih0[gr] + b_hh0[gr];
        bias1[g] = b_ih1[gr] + b_hh1[gr];
#pragma unroll
        for (int ks = 0; ks < 4; ++ks) {
            Whh0f[g][ks] = load_wfrag(w_hh0 + (size_t)gr * HID, ks * 32 + quad * 8);
            Wih1f[g][ks] = load_wfrag(w_ih1 + (size_t)gr * HID, ks * 32 + quad * 8);
            Whh1f[g][ks] = load_wfrag(w_hh1 + (size_t)gr * HID, ks * 32 + quad * 8);
        }
        half4 r;
#pragma unroll
        for (int j = 0; j < 4; ++j) {
            int k = quad * 4 + j;
            r[j] = (k < INSZ) ? (_Float16)w_ih0[gr * INSZ + k] : (_Float16)0.0f;
        }
        Wih0f[g] = r;
    }

    // ---- zero LDS (x pads + h ping-pong initial state) ----
    for (int i = tid; i < 2 * XCH * MB * XSTR / 2; i += NTHR) ((int*)&xs[0][0])[i] = 0;
    for (int i = tid; i < 2 * MB * HSTR / 2; i += NTHR) ((int*)&hA[0][0])[i] = 0;
    for (int i = tid; i < 2 * MB * HSTR / 2; i += NTHR) ((int*)&hB[0][0])[i] = 0;

    // ---- stage x chunk 0 (coalesced: thread = (row m, step s), 40B contiguous each) ----
    if (tid < 128) {
        const int m = tid >> 3, s = tid & 7;
        const float2* xp = (const float2*)(x + ((size_t)(b0 + m) * SEQ + s) * INSZ);
        _Float16* dst = &xs[0][0] + (s * MB + m) * XSTR;
#pragma unroll
        for (int p = 0; p < 5; ++p) {
            float2 v = xp[p];
            half2v h; h[0] = (_Float16)v.x; h[1] = (_Float16)v.y;
            *(half2v*)(dst + 2 * p) = h;
        }
    }
    __syncthreads();

    const int laneRd = m16 * HSTR + quad * 8;
    const int wrBase = (quad * 4) * HSTR + col;

    float c0[4] = {0.f, 0.f, 0.f, 0.f};
    float c1[4] = {0.f, 0.f, 0.f, 0.f};
    half2v xr[5];                     // packed fp16 x prefetch (threads 0..127)

    for (int t = 0; t <= SEQ; ++t) {
        const int p = t & 1;
        const int sub = t & 7;

        // coalesced x prefetch into regs every 8 steps (2 waves only)
        if (sub == 0 && t + XCH < SEQ && tid < 128) {
            const int m = tid >> 3, s = tid & 7;
            const float2* xp = (const float2*)(x + ((size_t)(b0 + m) * SEQ + (t + XCH + s)) * INSZ);
#pragma unroll
            for (int q = 0; q < 5; ++q) {
                float2 v = xp[q];
                half2v h; h[0] = (_Float16)v.x; h[1] = (_Float16)v.y;
                xr[q] = h;
            }
        }

        // shared A-fragments: h1[t-1] (used by L0 recurrence AND L1 input projection)
        const _Float16* haB = &hA[p ^ 1][0] + laneRd;
        half8 ha0 = *(const half8*)(haB);
        half8 ha1 = *(const half8*)(haB + 32);
        half8 ha2 = *(const half8*)(haB + 64);
        half8 ha3 = *(const half8*)(haB + 96);

        // ---- layer 0: time t ----
        if (t < SEQ) {
            half4 xa = *(const half4*)(&xs[(t >> 3) & 1][0] + (sub * MB + m16) * XSTR + quad * 4);
            floatx4 A0 = {bias0[0], bias0[0], bias0[0], bias0[0]};
            floatx4 A1 = {bias0[1], bias0[1], bias0[1], bias0[1]};
            floatx4 A2 = {bias0[2], bias0[2], bias0[2], bias0[2]};
            floatx4 A3 = {bias0[3], bias0[3], bias0[3], bias0[3]};
            A0 = MFMA16(xa, Wih0f[0], A0); A1 = MFMA16(xa, Wih0f[1], A1);
            A2 = MFMA16(xa, Wih0f[2], A2); A3 = MFMA16(xa, Wih0f[3], A3);
            A0 = MFMA32(ha0, Whh0f[0][0], A0); A1 = MFMA32(ha0, Whh0f[1][0], A1);
            A2 = MFMA32(ha0, Whh0f[2][0], A2); A3 = MFMA32(ha0, Whh0f[3][0], A3);
            A0 = MFMA32(ha1, Whh0f[0][1], A0); A1 = MFMA32(ha1, Whh0f[1][1], A1);
            A2 = MFMA32(ha1, Whh0f[2][1], A2); A3 = MFMA32(ha1, Whh0f[3][1], A3);
            A0 = MFMA32(ha2, Whh0f[0][2], A0); A1 = MFMA32(ha2, Whh0f[1][2], A1);
            A2 = MFMA32(ha2, Whh0f[2][2], A2); A3 = MFMA32(ha2, Whh0f[3][2], A3);
            A0 = MFMA32(ha3, Whh0f[0][3], A0); A1 = MFMA32(ha3, Whh0f[1][3], A1);
            A2 = MFMA32(ha3, Whh0f[2][3], A2); A3 = MFMA32(ha3, Whh0f[3][3], A3);

            _Float16* hw = &hA[p][0] + wrBase;
#pragma unroll
            for (int e = 0; e < 4; ++e) {
                float iv = sigmf(A0[e]);
                float fv = sigmf(A1[e]);
                float gv = tanhfast(A2[e]);
                float ov = sigmf(A3[e]);
                c0[e] = fv * c0[e] + iv * gv;
                hw[e * HSTR] = (_Float16)(ov * tanhfast(c0[e]));
            }
        }

        // commit prefetched x chunk to the other LDS buffer (no barrier needed: other buf)
        if (sub == 2 && t + 6 < SEQ && tid < 128) {
            const int m = tid >> 3, s = tid & 7;
            _Float16* dst = &xs[((t >> 3) + 1) & 1][0] + (s * MB + m) * XSTR;
#pragma unroll
            for (int q = 0; q < 5; ++q) *(half2v*)(dst + 2 * q) = xr[q];
        }

        // ---- layer 1: time t-1 ----
        if (t > 0) {
            const _Float16* hbB = &hB[p][0] + laneRd;
            half8 hb0 = *(const half8*)(hbB);
            half8 hb1 = *(const half8*)(hbB + 32);
            half8 hb2 = *(const half8*)(hbB + 64);
            half8 hb3 = *(const half8*)(hbB + 96);

            floatx4 B0 = {bias1[0], bias1[0], bias1[0], bias1[0]};
            floatx4 B1 = {bias1[1], bias1[1], bias1[1], bias1[1]};
            floatx4 B2 = {bias1[2], bias1[2], bias1[2], bias1[2]};
            floatx4 B3 = {bias1[3], bias1[3], bias1[3], bias1[3]};
            // input projection: h1[t-1] @ W_ih1^T  (reuses ha frags)
            B0 = MFMA32(ha0, Wih1f[0][0], B0); B1 = MFMA32(ha0, Wih1f[1][0], B1);
            B2 = MFMA32(ha0, Wih1f[2][0], B2); B3 = MFMA32(ha0, Wih1f[3][0], B3);
            B0 = MFMA32(ha1, Wih1f[0][1], B0); B1 = MFMA32(ha1, Wih1f[1][1], B1);
            B2 = MFMA32(ha1, Wih1f[2][1], B2); B3 = MFMA32(ha1, Wih1f[3][1], B3);
            B0 = MFMA32(ha2, Wih1f[0][2], B0); B1 = MFMA32(ha2, Wih1f[1][2], B1);
            B2 = MFMA32(ha2, Wih1f[2][2], B2); B3 = MFMA32(ha2, Wih1f[3][2], B3);
            B0 = MFMA32(ha3, Wih1f[0][3], B0); B1 = MFMA32(ha3, Wih1f[1][3], B1);
            B2 = MFMA32(ha3, Wih1f[2][3], B2); B3 = MFMA32(ha3, Wih1f[3][3], B3);
            // recurrent: h2[t-2] @ W_hh1^T
            B0 = MFMA32(hb0, Whh1f[0][0], B0); B1 = MFMA32(hb0, Whh1f[1][0], B1);
            B2 = MFMA32(hb0, Whh1f[2][0], B2); B3 = MFMA32(hb0, Whh1f[3][0], B3);
            B0 = MFMA32(hb1, Whh1f[0][1], B0); B1 = MFMA32(hb1, Whh1f[1][1], B1);
            B2 = MFMA32(hb1, Whh1f[2][1], B2); B3 = MFMA32(hb1, Whh1f[3][1], B3);
            B0 = MFMA32(hb2, Whh1f[0][2], B0); B1 = MFMA32(hb2, Whh1f[1][2], B1);
            B2 = MFMA32(hb2, Whh1f[2][2], B2); B3 = MFMA32(hb2, Whh1f[3][2], B3);
            B0 = MFMA32(hb3, Whh1f[0][3], B0); B1 = MFMA32(hb3, Whh1f[1][3], B1);
            B2 = MFMA32(hb3, Whh1f[2][3], B2); B3 = MFMA32(hb3, Whh1f[3][3], B3);

            _Float16* hw2 = &hB[p ^ 1][0] + wrBase;
#pragma unroll
            for (int e = 0; e < 4; ++e) {
                float iv = sigmf(B0[e]);
                float fv = sigmf(B1[e]);
                float gv = tanhfast(B2[e]);
                float ov = sigmf(B3[e]);
                c1[e] = fv * c1[e] + iv * gv;
                hw2[e * HSTR] = (_Float16)(ov * tanhfast(c1[e]));
            }
        }
        __syncthreads();
    }

    // ---- FC epilogue: final h2[511] is in hB[1] (t=512: p=0, wrote hB[p^1]=hB[1]) ----
    if (tid < 160) {
        const int cls = tid >> 4, b = tid & 15;
        float a = fc_b[cls];
        const float* wr = fc_w + cls * HID;
        const _Float16* hb1 = &hB[1][0] + b * HSTR;
#pragma unroll 8
        for (int k = 0; k < HID; ++k) a += wr[k] * (float)hb1[k];
        out[(size_t)(b0 + b) * 10 + cls] = a;
    }
}

extern "C" void kernel_launch(void* const* d_in, const int* in_sizes, int n_in,
                              void* d_out, int out_size, void* d_ws, size_t ws_size,
                              hipStream_t stream) {
    (void)in_sizes; (void)n_in; (void)out_size; (void)d_ws; (void)ws_size;
    const float* x     = (const float*)d_in[0];
    const float* w_ih0 = (const float*)d_in[1];
    const float* w_hh0 = (const float*)d_in[2];
    const float* b_ih0 = (const float*)d_in[3];
    const float* b_hh0 = (const float*)d_in[4];
    const float* w_ih1 = (const float*)d_in[5];
    const float* w_hh1 = (const float*)d_in[6];
    const float* b_ih1 = (const float*)d_in[7];
    const float* b_hh1 = (const float*)d_in[8];
    const float* fc_w  = (const float*)d_in[9];
    const float* fc_b  = (const float*)d_in[10];
    float* out = (float*)d_out;

    lstm_fused3<<<NBLK, NTHR, 0, stream>>>(x, w_ih0, w_hh0, b_ih0, b_hh0,
                                           w_ih1, w_hh1, b_ih1, b_hh1,
                                           fc_w, fc_b, out);
}